// Round 11
// baseline (416.758 us; speedup 1.0000x reference)
//
#include <hip/hip_runtime.h>
#include <hip/hip_bf16.h>

constexpr int MTOK = 1024;   // B*S
constexpr int HDIM = 2048;
constexpr int IDIM = 2048;
constexpr int NEXP = 16;
constexpr int TOPK = 4;
constexpr int NA   = MTOK * TOPK;   // 4096 assignments

#define ALPHA_C 1.702f
#define LIMIT_C 7.0f
#define RMS_EPS 1e-5f

using short8 = __attribute__((ext_vector_type(8))) short;
using f32x4  = __attribute__((ext_vector_type(4))) float;

__device__ __forceinline__ unsigned short f2bf(float f) {
    unsigned u = __builtin_bit_cast(unsigned, f);
    u += 0x7fffu + ((u >> 16) & 1u);     // round-to-nearest-even
    return (unsigned short)(u >> 16);
}

__device__ __forceinline__ unsigned pack2bf(float lo, float hi) {
    return (unsigned)f2bf(lo) | ((unsigned)f2bf(hi) << 16);
}

__device__ __forceinline__ short8 cvt8(const float4 a, const float4 b) {
    union { short8 s; unsigned u[4]; } r;
    r.u[0] = pack2bf(a.x, a.y);
    r.u[1] = pack2bf(a.z, a.w);
    r.u[2] = pack2bf(b.x, b.y);
    r.u[3] = pack2bf(b.z, b.w);
    return r.s;
}

// async global->LDS, 16B/lane; LDS dest = wave-uniform base + lane*16
__device__ __forceinline__ void gload16(const void* g, void* l) {
    __builtin_amdgcn_global_load_lds(
        (const __attribute__((address_space(1))) void*)g,
        (__attribute__((address_space(3))) void*)l, 16, 0, 0);
}

#define WAITV(n)  asm volatile("s_waitcnt vmcnt(" #n ")" ::: "memory")
#define WAITL0    asm volatile("s_waitcnt lgkmcnt(0)" ::: "memory")
#define BARRIER   asm volatile("s_barrier" ::: "memory")
#define SCHEDB    __builtin_amdgcn_sched_barrier(0)

// ---------------- RMSNorm + router + top-k ----------------
__global__ __launch_bounds__(256) void k_router(
    const float* __restrict__ x, const float* __restrict__ norm_w,
    const float* __restrict__ gate_w, const float* __restrict__ gate_b,
    unsigned short* __restrict__ t_bf,
    int* __restrict__ counts, int* __restrict__ idx_of,
    int* __restrict__ slot_of, float* __restrict__ gate_mk)
{
    __shared__ float t_lds[HDIM];
    __shared__ float red[4];
    __shared__ float logits[NEXP];

    const int m   = blockIdx.x;
    const int tid = threadIdx.x;
    const float* xr = x + (size_t)m * HDIM;

    float4 v0 = ((const float4*)xr)[tid * 2];
    float4 v1 = ((const float4*)xr)[tid * 2 + 1];
    float ss = v0.x*v0.x + v0.y*v0.y + v0.z*v0.z + v0.w*v0.w
             + v1.x*v1.x + v1.y*v1.y + v1.z*v1.z + v1.w*v1.w;
    #pragma unroll
    for (int off = 32; off > 0; off >>= 1) ss += __shfl_down(ss, off);
    if ((tid & 63) == 0) red[tid >> 6] = ss;
    __syncthreads();
    float tot = red[0] + red[1] + red[2] + red[3];
    float scale = rsqrtf(tot / (float)HDIM + RMS_EPS);

    float4 n0 = ((const float4*)norm_w)[tid * 2];
    float4 n1 = ((const float4*)norm_w)[tid * 2 + 1];
    float t[8];
    t[0]=v0.x*scale*n0.x; t[1]=v0.y*scale*n0.y; t[2]=v0.z*scale*n0.z; t[3]=v0.w*scale*n0.w;
    t[4]=v1.x*scale*n1.x; t[5]=v1.y*scale*n1.y; t[6]=v1.z*scale*n1.z; t[7]=v1.w*scale*n1.w;
    short8 pk;
    #pragma unroll
    for (int j = 0; j < 8; ++j) {
        t_lds[tid * 8 + j] = t[j];
        pk[j] = (short)f2bf(t[j]);
    }
    *(short8*)(t_bf + (size_t)m * HDIM + tid * 8) = pk;
    __syncthreads();

    const int e = tid >> 4, j = tid & 15;
    const float4* gw4 = (const float4*)(gate_w + (size_t)e * HDIM);
    const float4* tl4 = (const float4*)t_lds;
    float part = 0.f;
    for (int h4 = j; h4 < HDIM / 4; h4 += 16) {
        float4 g = gw4[h4], tv = tl4[h4];
        part += g.x*tv.x + g.y*tv.y + g.z*tv.z + g.w*tv.w;
    }
    #pragma unroll
    for (int off = 8; off > 0; off >>= 1) part += __shfl_xor(part, off);
    if (j == 0) logits[e] = part + gate_b[e];
    __syncthreads();

    if (tid == 0) {
        float lv[NEXP];
        #pragma unroll
        for (int q = 0; q < NEXP; ++q) lv[q] = logits[q];
        int   sel[TOPK];
        float sv[TOPK];
        #pragma unroll
        for (int k = 0; k < TOPK; ++k) {
            float best = -1e30f; int bi = 0;
            for (int q = 0; q < NEXP; ++q)
                if (lv[q] > best) { best = lv[q]; bi = q; }
            sel[k] = bi; sv[k] = best; lv[bi] = -1e30f;
        }
        float mx = sv[0], s = 0.f, g[TOPK];
        #pragma unroll
        for (int k = 0; k < TOPK; ++k) { g[k] = __expf(sv[k] - mx); s += g[k]; }
        float inv = 1.f / s;
        #pragma unroll
        for (int k = 0; k < TOPK; ++k) {
            int a = m * TOPK + k;
            int slot = atomicAdd(&counts[sel[k]], 1);
            idx_of[a]  = sel[k];
            slot_of[a] = slot;
            gate_mk[a] = g[k] * inv;
        }
    }
}

// ---------------- scatter tokens into compact per-expert rows ----------------
__global__ void k_remap(const int* __restrict__ idx_of, const int* __restrict__ slot_of,
                        const int* __restrict__ counts,
                        int* __restrict__ token_of, int* __restrict__ rowidx)
{
    int a = blockIdx.x * blockDim.x + threadIdx.x;
    if (a >= NA) return;
    int e = idx_of[a];
    int off = 0;
    for (int q = 0; q < NEXP; ++q) off += (q < e) ? counts[q] : 0;
    int r = off + slot_of[a];
    token_of[r] = a >> 2;
    rowidx[a]   = r;
}

// ---------------- GEMM1: counted-vmcnt deep pipeline ----------------
// BM=320 x 64 cols, BK=32, NT=64. B: global_load_lds -> 4 fp32 LDS buffers
// (8KB each), issued 3 tiles ahead; s_waitcnt vmcnt(9) keeps 2 B-tiles
// (4KB/wave -> 32KB/CU) in flight across the raw s_barrier. A: direct-to-reg
// even/odd sets. B fp32 chunks stored XOR-swizzled (chunk^(col&7), applied
// to the GLOBAL source addr) so consume-side ds_read_b128 is conflict-free.
__global__ __launch_bounds__(256, 2) void k_gemm1(
    const unsigned short* __restrict__ t_bf,
    const float* __restrict__ w1, const float* __restrict__ b1,
    const int* __restrict__ counts, const int* __restrict__ token_of,
    unsigned short* __restrict__ act)
{
    __shared__ float lB[4][2048];   // 4 bufs x (64 cols x 32 fp32) = 32 KB

    const int e = blockIdx.z;
    int ne = 0, roff = 0;
    #pragma unroll
    for (int q = 0; q < NEXP; ++q) {
        int cq = counts[q];
        roff += (q < e) ? cq : 0;
        ne    = (q == e) ? cq : ne;
    }
    const int brow = blockIdx.y * 320;
    if (brow >= ne) return;
    const int i0 = blockIdx.x * 32;
    const int tid = threadIdx.x;

    const int wv = tid >> 6, ln = tid & 63;
    const int lr = ln & 15, lk = ln >> 4;

    // A gather pointers (wave-exclusive rows)
    const unsigned short* aptr[5];
    #pragma unroll
    for (int mf = 0; mf < 5; ++mf) {
        int rg = brow + wv * 80 + mf * 16 + lr;
        int tok = token_of[roff + (rg < ne ? rg : 0)];
        aptr[mf] = t_bf + (size_t)tok * HDIM + lk * 8;
    }

    // B staging: wave wv, slots j=0,1 cover cols (wv*2+j)*8 + ln/8; chunk = ln&7
    const int cj0 = (wv * 2 + 0) * 8 + (ln >> 3);
    const int cj1 = (wv * 2 + 1) * 8 + (ln >> 3);
    const int c2  = ln & 7;
    const int o0 = (cj0 < 32) ? (2 * (i0 + cj0)) : (2 * (i0 + cj0 - 32) + 1);
    const int o1 = (cj1 < 32) ? (2 * (i0 + cj1)) : (2 * (i0 + cj1 - 32) + 1);
    const float* bs0 = w1 + ((size_t)e * (2 * IDIM) + o0) * HDIM + (c2 ^ (cj0 & 7)) * 4;
    const float* bs1 = w1 + ((size_t)e * (2 * IDIM) + o1) * HDIM + (c2 ^ (cj1 & 7)) * 4;
    float* lw0 = &lB[0][(wv * 2 + 0) * 256];
    float* lw1 = &lB[0][(wv * 2 + 1) * 256];

    short8 aE[5], aO[5];
    f32x4  acc[5][4] = {};
    constexpr int NT = 64;

#define STAGE1(T_) { gload16(bs0 + (T_) * 32, lw0 + ((T_) & 3) * 2048); \
                     gload16(bs1 + (T_) * 32, lw1 + ((T_) & 3) * 2048); }

#define COMPUTE1(T_, AU)                                                                 \
    {                                                                                    \
        short8 bfr[4];                                                                   \
        _Pragma("unroll")                                                                \
        for (int n = 0; n < 4; ++n) {                                                    \
            const int c_ = n * 16 + lr;                                                  \
            const float* cb = &lB[(T_) & 3][0] + c_ * 32;                                \
            float4 u0 = *(const float4*)(cb + (((2 * lk)     ^ (c_ & 7)) * 4));          \
            float4 u1 = *(const float4*)(cb + (((2 * lk + 1) ^ (c_ & 7)) * 4));          \
            bfr[n] = cvt8(u0, u1);                                                       \
        }                                                                                \
        _Pragma("unroll")                                                                \
        for (int mf = 0; mf < 5; ++mf)                                                   \
            _Pragma("unroll")                                                            \
            for (int n = 0; n < 4; ++n)                                                  \
                acc[mf][n] = __builtin_amdgcn_mfma_f32_16x16x32_bf16(                    \
                    AU[mf], bfr[n], acc[mf][n], 0, 0, 0);                                \
    }

#define LOADA1(T_, AP)                                                                   \
    {                                                                                    \
        _Pragma("unroll")                                                                \
        for (int mf = 0; mf < 5; ++mf)                                                   \
            AP[mf] = *(const short8*)(aptr[mf] + (T_) * 32);                             \
    }

    // prologue: B0,B1 ; A0 ; B2  (order pinned) -> vmcnt(9) drains B0 -> barrier
    STAGE1(0) STAGE1(1)
    SCHEDB;
    LOADA1(0, aE)
    SCHEDB;
    STAGE1(2)
    SCHEDB;
    WAITV(9);
    BARRIER;

    // main loop t = 0..59 (pairs); queue/wave: [B(t+1),B(t+2),A(t),...]
    for (int t2 = 0; t2 < 30; ++t2) {
        const int t = t2 * 2;
        // even step t
        LOADA1(t + 1, aO) SCHEDB;
        STAGE1(t + 3)     SCHEDB;
        WAITV(9); SCHEDB;
        COMPUTE1(t, aE)
        WAITL0; BARRIER;
        // odd step t+1
        LOADA1(t + 2, aE) SCHEDB;
        STAGE1(t + 4)     SCHEDB;
        WAITV(9); SCHEDB;
        COMPUTE1(t + 1, aO)
        WAITL0; BARRIER;
    }
    // tails t=60..63 with exact vmcnt ladder
    LOADA1(61, aO) SCHEDB; STAGE1(63) SCHEDB; WAITV(9); SCHEDB;
    COMPUTE1(60, aE) WAITL0; BARRIER;
    LOADA1(62, aE) SCHEDB; WAITV(7); SCHEDB;
    COMPUTE1(61, aO) WAITL0; BARRIER;
    LOADA1(63, aO) SCHEDB; WAITV(5); SCHEDB;
    COMPUTE1(62, aE) WAITL0; BARRIER;
    WAITV(0); SCHEDB;
    COMPUTE1(63, aO)

#undef STAGE1
#undef COMPUTE1
#undef LOADA1

    #pragma unroll
    for (int n = 0; n < 2; ++n) {
        const int i = i0 + n * 16 + lr;
        const float ba = b1[(size_t)e * (2 * IDIM) + 2 * i];
        const float bb = b1[(size_t)e * (2 * IDIM) + 2 * i + 1];
        #pragma unroll
        for (int mf = 0; mf < 5; ++mf) {
            #pragma unroll
            for (int r = 0; r < 4; ++r) {
                const int rg = brow + wv * 80 + mf * 16 + lk * 4 + r;
                if (rg < ne) {
                    float ha = acc[mf][n][r] + ba;
                    float hb = acc[mf][n + 2][r] + bb;
                    float a = fminf(ha, LIMIT_C);
                    float b = fminf(fmaxf(hb, -LIMIT_C), LIMIT_C);
                    float s = 1.f / (1.f + __expf(-ALPHA_C * a));
                    act[(size_t)(roff + rg) * IDIM + i] = f2bf(a * s * (b + 1.f));
                }
            }
        }
    }
}

// ---------------- GEMM2 + bias -> ybuf (bf16, un-gated) ----------------
__global__ __launch_bounds__(256, 2) void k_gemm2(
    const unsigned short* __restrict__ act,
    const float* __restrict__ w2, const float* __restrict__ b2,
    const int* __restrict__ counts, const int* __restrict__ token_of,
    unsigned short* __restrict__ ybuf)
{
    __shared__ float lB[4][2048];

    const int e = blockIdx.z;
    int ne = 0, roff = 0;
    #pragma unroll
    for (int q = 0; q < NEXP; ++q) {
        int cq = counts[q];
        roff += (q < e) ? cq : 0;
        ne    = (q == e) ? cq : ne;
    }
    const int brow = blockIdx.y * 320;
    if (brow >= ne) return;
    const int d0 = blockIdx.x * 64;
    const int tid = threadIdx.x;

    const int wv = tid >> 6, ln = tid & 63;
    const int lr = ln & 15, lk = ln >> 4;

    const unsigned short* aptr[5];
    #pragma unroll
    for (int mf = 0; mf < 5; ++mf) {
        int rg = brow + wv * 80 + mf * 16 + lr;
        int rc = (rg < ne) ? rg : 0;
        aptr[mf] = act + (size_t)(roff + rc) * IDIM + lk * 8;
    }

    const int cj0 = (wv * 2 + 0) * 8 + (ln >> 3);
    const int cj1 = (wv * 2 + 1) * 8 + (ln >> 3);
    const int c2  = ln & 7;
    const float* bs0 = w2 + ((size_t)e * HDIM + d0 + cj0) * IDIM + (c2 ^ (cj0 & 7)) * 4;
    const float* bs1 = w2 + ((size_t)e * HDIM + d0 + cj1) * IDIM + (c2 ^ (cj1 & 7)) * 4;
    float* lw0 = &lB[0][(wv * 2 + 0) * 256];
    float* lw1 = &lB[0][(wv * 2 + 1) * 256];

    short8 aE[5], aO[5];
    f32x4  acc[5][4] = {};
    constexpr int NT = 64;
    (void)NT;

#define STAGE2(T_) { gload16(bs0 + (T_) * 32, lw0 + ((T_) & 3) * 2048); \
                     gload16(bs1 + (T_) * 32, lw1 + ((T_) & 3) * 2048); }

#define COMPUTE2(T_, AU)                                                                 \
    {                                                                                    \
        short8 bfr[4];                                                                   \
        _Pragma("unroll")                                                                \
        for (int n = 0; n < 4; ++n) {                                                    \
            const int c_ = n * 16 + lr;                                                  \
            const float* cb = &lB[(T_) & 3][0] + c_ * 32;                                \
            float4 u0 = *(const float4*)(cb + (((2 * lk)     ^ (c_ & 7)) * 4));          \
            float4 u1 = *(const float4*)(cb + (((2 * lk + 1) ^ (c_ & 7)) * 4));          \
            bfr[n] = cvt8(u0, u1);                                                       \
        }                                                                                \
        _Pragma("unroll")                                                                \
        for (int mf = 0; mf < 5; ++mf)                                                   \
            _Pragma("unroll")                                                            \
            for (int n = 0; n < 4; ++n)                                                  \
                acc[mf][n] = __builtin_amdgcn_mfma_f32_16x16x32_bf16(                    \
                    AU[mf], bfr[n], acc[mf][n], 0, 0, 0);                                \
    }

#define LOADA2(T_, AP)                                                                   \
    {                                                                                    \
        _Pragma("unroll")                                                                \
        for (int mf = 0; mf < 5; ++mf)                                                   \
            AP[mf] = *(const short8*)(aptr[mf] + (T_) * 32);                             \
    }

    STAGE2(0) STAGE2(1)
    SCHEDB;
    LOADA2(0, aE)
    SCHEDB;
    STAGE2(2)
    SCHEDB;
    WAITV(9);
    BARRIER;

    for (int t2 = 0; t2 < 30; ++t2) {
        const int t = t2 * 2;
        LOADA2(t + 1, aO) SCHEDB;
        STAGE2(t + 3)     SCHEDB;
        WAITV(9); SCHEDB;
        COMPUTE2(t, aE)
        WAITL0; BARRIER;
        LOADA2(t + 2, aE) SCHEDB;
        STAGE2(t + 4)     SCHEDB;
        WAITV(9); SCHEDB;
        COMPUTE2(t + 1, aO)
        WAITL0; BARRIER;
    }
    LOADA2(61, aO) SCHEDB; STAGE2(63) SCHEDB; WAITV(9); SCHEDB;
    COMPUTE2(60, aE) WAITL0; BARRIER;
    LOADA2(62, aE) SCHEDB; WAITV(7); SCHEDB;
    COMPUTE2(61, aO) WAITL0; BARRIER;
    LOADA2(63, aO) SCHEDB; WAITV(5); SCHEDB;
    COMPUTE2(62, aE) WAITL0; BARRIER;
    WAITV(0); SCHEDB;
    COMPUTE2(63, aO)

#undef STAGE2
#undef COMPUTE2
#undef LOADA2

    #pragma unroll
    for (int mf = 0; mf < 5; ++mf) {
        #pragma unroll
        for (int r = 0; r < 4; ++r) {
            const int rg = brow + wv * 80 + mf * 16 + lk * 4 + r;
            if (rg >= ne) continue;
            unsigned short* yrow = ybuf + (size_t)(roff + rg) * HDIM;
            #pragma unroll
            for (int n = 0; n < 4; ++n) {
                const int d = d0 + n * 16 + lr;
                yrow[d] = f2bf(acc[mf][n][r] + b2[(size_t)e * HDIM + d]);
            }
        }
    }
}

// ---------------- combine: out = x + sum_k gate_k * ybuf[row_k] ----------------
__global__ __launch_bounds__(256) void k_comb(
    const float* __restrict__ x, const unsigned short* __restrict__ ybuf,
    const int* __restrict__ rowidx, const float* __restrict__ gate_mk,
    float* __restrict__ out)
{
    __shared__ int   rws[TOPK];
    __shared__ float gws[TOPK];
    const int m = blockIdx.x;
    const int tid = threadIdx.x;
    if (tid < TOPK) {
        rws[tid] = rowidx[m * TOPK + tid];
        gws[tid] = gate_mk[m * TOPK + tid];
    }
    __syncthreads();
    const int d = tid * 8;
    float4 o0 = ((const float4*)(x + (size_t)m * HDIM + d))[0];
    float4 o1 = ((const float4*)(x + (size_t)m * HDIM + d))[1];
    #pragma unroll
    for (int k = 0; k < TOPK; ++k) {
        const float g = gws[k];
        short8 y = *(const short8*)(ybuf + (size_t)rws[k] * HDIM + d);
        float yv[8];
        #pragma unroll
        for (int j = 0; j < 8; ++j) {
            unsigned u = ((unsigned)(unsigned short)y[j]) << 16;
            yv[j] = __builtin_bit_cast(float, u);
        }
        o0.x += g * yv[0]; o0.y += g * yv[1]; o0.z += g * yv[2]; o0.w += g * yv[3];
        o1.x += g * yv[4]; o1.y += g * yv[5]; o1.z += g * yv[6]; o1.w += g * yv[7];
    }
    ((float4*)(out + (size_t)m * HDIM + d))[0] = o0;
    ((float4*)(out + (size_t)m * HDIM + d))[1] = o1;
}

extern "C" void kernel_launch(void* const* d_in, const int* in_sizes, int n_in,
                              void* d_out, int out_size, void* d_ws, size_t ws_size,
                              hipStream_t stream) {
    const float* x      = (const float*)d_in[0];
    const float* norm_w = (const float*)d_in[1];
    const float* gate_w = (const float*)d_in[2];
    const float* gate_b = (const float*)d_in[3];
    const float* w1     = (const float*)d_in[4];
    const float* b1     = (const float*)d_in[5];
    const float* w2     = (const float*)d_in[6];
    const float* b2     = (const float*)d_in[7];
    float* out = (float*)d_out;

    char* ws = (char*)d_ws;
    size_t off = 0;
    unsigned short* t_bf = (unsigned short*)(ws + off); off += (size_t)MTOK * HDIM * 2;  // 4 MB
    unsigned short* actb = (unsigned short*)(ws + off); off += (size_t)NA * IDIM * 2;    // 16.8 MB
    unsigned short* ybuf = (unsigned short*)(ws + off); off += (size_t)NA * HDIM * 2;    // 16.8 MB
    int*   counts   = (int*)(ws + off);   off += 256;
    int*   idx_of   = (int*)(ws + off);   off += (size_t)NA * 4;
    int*   slot_of  = (int*)(ws + off);   off += (size_t)NA * 4;
    float* gate_mk  = (float*)(ws + off); off += (size_t)NA * 4;
    int*   token_of = (int*)(ws + off);   off += (size_t)NA * 4;
    int*   rowidx   = (int*)(ws + off);   off += (size_t)NA * 4;

    (void)hipMemsetAsync(counts, 0, 256, stream);
    k_router<<<MTOK, 256, 0, stream>>>(x, norm_w, gate_w, gate_b, t_bf,
                                       counts, idx_of, slot_of, gate_mk);
    k_remap<<<NA / 256, 256, 0, stream>>>(idx_of, slot_of, counts,
                                          token_of, rowidx);
    k_gemm1<<<dim3(IDIM / 32, (MTOK + 319) / 320, NEXP), 256, 0, stream>>>(
        t_bf, w1, b1, counts, token_of, actb);
    k_gemm2<<<dim3(HDIM / 64, (MTOK + 319) / 320, NEXP), 256, 0, stream>>>(
        actb, w2, b2, counts, token_of, ybuf);
    k_comb<<<MTOK, 256, 0, stream>>>(x, ybuf, rowidx, gate_mk, out);
}